// Round 1
// baseline (6808.736 us; speedup 1.0000x reference)
//
#include <hip/hip_runtime.h>
#include <math.h>

// Problem dims (fixed per reference)
#define NB 1024   // batch
#define L_ 128    // objects
#define E_ 256    // embed dim
#define H_ 512    // hidden
#define T_ 20     // timesteps

// ---------------------------------------------------------------------------
// Mask-dtype detector: if input_mask is int32 (0/1), every byte at offset
// 4i+1 in the first 128KiB is 0. If it's 1-byte bool, ~half are 1.
// Reads are in-bounds under BOTH interpretations.
// ---------------------------------------------------------------------------
__global__ __launch_bounds__(256) void detect_mask(const unsigned char* __restrict__ mask,
                                                   int* __restrict__ flag) {
    int i = blockIdx.x * 256 + threadIdx.x;          // i < 32768
    if (mask[4 * i + 1] != 0) flag[0] = 1;           // benign race, same value
}

// ---------------------------------------------------------------------------
// attend: one block per batch. scores = M[b] @ pq[b]; mask; softmax;
// applied = w @ M[b]. Writes w to out iff clip(lengths[b]) == t.
// ---------------------------------------------------------------------------
__global__ __launch_bounds__(256) void attend_kernel(
    const float* __restrict__ M, const unsigned char* __restrict__ maskB,
    const int* __restrict__ flag, const float* __restrict__ pq,
    const int* __restrict__ lengths, float* __restrict__ applied,
    float* __restrict__ out, int t, int writeApplied)
{
    const int b = blockIdx.x;
    const int tid = threadIdx.x;
    __shared__ float pq_s[E_];
    __shared__ float sc[L_];
    __shared__ float red[8];

    pq_s[tid] = pq[b * E_ + tid];
    __syncthreads();

    const int wave = tid >> 6, lane = tid & 63;
    const float* Mb = M + (size_t)b * L_ * E_;
    const int isByte = flag[0];
    const int* maskI = (const int*)maskB;

    // Phase A: scores. One wave per row; lane reads float4 (coalesced 1KB/row).
    for (int l = wave; l < L_; l += 4) {
        float4 mv = *reinterpret_cast<const float4*>(Mb + l * E_ + lane * 4);
        float4 pv = *reinterpret_cast<const float4*>(pq_s + lane * 4);
        float s = mv.x * pv.x + mv.y * pv.y + mv.z * pv.z + mv.w * pv.w;
        #pragma unroll
        for (int off = 32; off > 0; off >>= 1) s += __shfl_down(s, off, 64);
        if (lane == 0) {
            int msk = isByte ? (int)maskB[b * L_ + l] : maskI[b * L_ + l];
            sc[l] = msk ? -INFINITY : s;   // mask True -> -inf (matches reference)
        }
    }
    __syncthreads();

    // Phase B: softmax over 128 (threads >=128 contribute neutral elements)
    float v = (tid < L_) ? sc[tid] : -INFINITY;
    float m = v;
    #pragma unroll
    for (int off = 32; off > 0; off >>= 1) m = fmaxf(m, __shfl_down(m, off, 64));
    if (lane == 0) red[wave] = m;
    __syncthreads();
    const float mx = fmaxf(fmaxf(red[0], red[1]), fmaxf(red[2], red[3]));
    const float e = (tid < L_) ? __expf(v - mx) : 0.0f;   // exp(-inf)=0 for masked
    float s2 = e;
    #pragma unroll
    for (int off = 32; off > 0; off >>= 1) s2 += __shfl_down(s2, off, 64);
    if (lane == 0) red[4 + wave] = s2;
    __syncthreads();
    const float tot = red[4] + red[5] + red[6] + red[7];
    const float wgt = e / tot;
    if (tid < L_) sc[tid] = wgt;          // reuse sc as weights (v already consumed)
    __syncthreads();

    int lc = lengths[b];
    lc = lc < 0 ? 0 : (lc > T_ ? T_ : lc);
    if (lc == t && tid < L_) out[(size_t)b * L_ + tid] = wgt;

    // Phase C: applied[e] = sum_l w[l]*M[b,l,e]; thread=e, coalesced over e.
    if (writeApplied) {
        float acc = 0.0f;
        #pragma unroll 8
        for (int l = 0; l < L_; ++l) acc += sc[l] * Mb[l * E_ + tid];
        applied[b * E_ + tid] = acc;
    }
}

// ---------------------------------------------------------------------------
// Generic 64x64x16 f32 tiled GEMM: C[m,n] = sum_k A[m,k]*B[n,k] + bias[n]
// A is a virtual concat: cols [0,K1) from A1 (row stride K1),
//                        cols [K1,Kn) from A2 (row stride Kn-K1).
// LDS tiles stored k-major (transposed) so compute reads are float4.
// ---------------------------------------------------------------------------
__global__ __launch_bounds__(256) void gemm64(
    const float* __restrict__ A1, const float* __restrict__ A2,
    const float* __restrict__ B, const float* __restrict__ bias,
    float* __restrict__ C, int Nn, int Kn, int K1)
{
    __shared__ float AsT[16][68];
    __shared__ float BsT[16][68];
    const int tid = threadIdx.x;
    const int tx = tid & 15, ty = tid >> 4;
    const int n0 = blockIdx.x * 64, m0 = blockIdx.y * 64;
    float acc[4][4] = {};
    const int lr = tid >> 2;            // 0..63: tile row to load
    const int lc4 = (tid & 3) * 4;      // 0,4,8,12: k offset

    for (int k0 = 0; k0 < Kn; k0 += 16) {
        const int k = k0 + lc4;
        float4 av;
        if (k < K1)
            av = *reinterpret_cast<const float4*>(A1 + (size_t)(m0 + lr) * K1 + k);
        else
            av = *reinterpret_cast<const float4*>(A2 + (size_t)(m0 + lr) * (Kn - K1) + (k - K1));
        float4 bv = *reinterpret_cast<const float4*>(B + (size_t)(n0 + lr) * Kn + k);
        AsT[lc4 + 0][lr] = av.x; AsT[lc4 + 1][lr] = av.y;
        AsT[lc4 + 2][lr] = av.z; AsT[lc4 + 3][lr] = av.w;
        BsT[lc4 + 0][lr] = bv.x; BsT[lc4 + 1][lr] = bv.y;
        BsT[lc4 + 2][lr] = bv.z; BsT[lc4 + 3][lr] = bv.w;
        __syncthreads();
        #pragma unroll
        for (int kk = 0; kk < 16; ++kk) {
            float4 a  = *reinterpret_cast<const float4*>(&AsT[kk][ty * 4]);
            float4 bb = *reinterpret_cast<const float4*>(&BsT[kk][tx * 4]);
            float aa[4] = {a.x, a.y, a.z, a.w};
            float bbv[4] = {bb.x, bb.y, bb.z, bb.w};
            #pragma unroll
            for (int i = 0; i < 4; ++i)
                #pragma unroll
                for (int j = 0; j < 4; ++j)
                    acc[i][j] += aa[i] * bbv[j];
        }
        __syncthreads();
    }
    const int col = n0 + tx * 4;
    #pragma unroll
    for (int i = 0; i < 4; ++i) {
        const int row = m0 + ty * 4 + i;
        float4 o;
        o.x = acc[i][0] + bias[col + 0];
        o.y = acc[i][1] + bias[col + 1];
        o.z = acc[i][2] + bias[col + 2];
        o.w = acc[i][3] + bias[col + 3];
        *reinterpret_cast<float4*>(C + (size_t)row * Nn + col) = o;
    }
}

// ---------------------------------------------------------------------------
// Fused gates GEMM + LSTM cell. Tile: 64 batches x 64 hidden cols x 4 gates.
// A = [emb[msg[:,t]] (256) | att_out (512)], B = [W_ih | W_hh] rows g*512+j.
// ---------------------------------------------------------------------------
__global__ __launch_bounds__(256) void gates_lstm(
    const float* __restrict__ emb, const int* __restrict__ msg,
    const float* __restrict__ att, const float* __restrict__ W_ih,
    const float* __restrict__ W_hh, const float* __restrict__ b_ih,
    const float* __restrict__ b_hh, float* __restrict__ h,
    float* __restrict__ c, int t)
{
    __shared__ float AsT[16][68];
    __shared__ float BsT[16][260];
    const int tid = threadIdx.x;
    const int tx = tid & 15, ty = tid >> 4;
    const int j0 = blockIdx.x * 64, b0 = blockIdx.y * 64;
    float acc[4][4][4] = {};               // [gate][brow][jcol]
    const int lr = tid >> 2;
    const int lc4 = (tid & 3) * 4;

    for (int k0 = 0; k0 < 768; k0 += 16) {
        const int k = k0 + lc4;
        // A tile
        float4 av;
        const int bb_ = b0 + lr;
        if (k < 256) {
            const int tok = msg[bb_ * T_ + t];
            av = *reinterpret_cast<const float4*>(emb + (size_t)tok * E_ + k);
        } else {
            av = *reinterpret_cast<const float4*>(att + (size_t)bb_ * H_ + (k - 256));
        }
        AsT[lc4 + 0][lr] = av.x; AsT[lc4 + 1][lr] = av.y;
        AsT[lc4 + 2][lr] = av.z; AsT[lc4 + 3][lr] = av.w;
        // B tile: 256 rows = 4 gates x 64 cols
        #pragma unroll
        for (int ch = 0; ch < 4; ++ch) {
            const int row = ch * 64 + lr;
            const int g = row >> 6, jj = row & 63;
            const int r = g * 512 + j0 + jj;
            float4 bv;
            if (k < 256) bv = *reinterpret_cast<const float4*>(W_ih + (size_t)r * 256 + k);
            else         bv = *reinterpret_cast<const float4*>(W_hh + (size_t)r * 512 + (k - 256));
            BsT[lc4 + 0][row] = bv.x; BsT[lc4 + 1][row] = bv.y;
            BsT[lc4 + 2][row] = bv.z; BsT[lc4 + 3][row] = bv.w;
        }
        __syncthreads();
        #pragma unroll
        for (int kk = 0; kk < 16; ++kk) {
            float4 a = *reinterpret_cast<const float4*>(&AsT[kk][ty * 4]);
            float aa[4] = {a.x, a.y, a.z, a.w};
            #pragma unroll
            for (int g = 0; g < 4; ++g) {
                float4 bg = *reinterpret_cast<const float4*>(&BsT[kk][g * 64 + tx * 4]);
                float bv4[4] = {bg.x, bg.y, bg.z, bg.w};
                #pragma unroll
                for (int i = 0; i < 4; ++i)
                    #pragma unroll
                    for (int j = 0; j < 4; ++j)
                        acc[g][i][j] += aa[i] * bv4[j];
            }
        }
        __syncthreads();
    }
    // epilogue: LSTM cell
    #pragma unroll
    for (int i = 0; i < 4; ++i) {
        const int b = b0 + ty * 4 + i;
        #pragma unroll
        for (int j = 0; j < 4; ++j) {
            const int jc = j0 + tx * 4 + j;
            const float gi = acc[0][i][j] + b_ih[jc]        + b_hh[jc];
            const float gf = acc[1][i][j] + b_ih[512 + jc]  + b_hh[512 + jc];
            const float gg = acc[2][i][j] + b_ih[1024 + jc] + b_hh[1024 + jc];
            const float go = acc[3][i][j] + b_ih[1536 + jc] + b_hh[1536 + jc];
            const float si = 1.0f / (1.0f + __expf(-gi));
            const float sf = 1.0f / (1.0f + __expf(-gf));
            const float so = 1.0f / (1.0f + __expf(-go));
            const float tg = tanhf(gg);
            const size_t idx = (size_t)b * H_ + jc;
            const float cn = sf * c[idx] + si * tg;
            c[idx] = cn;
            h[idx] = so * tanhf(cn);
        }
    }
}

// ---------------------------------------------------------------------------
extern "C" void kernel_launch(void* const* d_in, const int* in_sizes, int n_in,
                              void* d_out, int out_size, void* d_ws, size_t ws_size,
                              hipStream_t stream)
{
    const int*   msg     = (const int*)d_in[0];
    const float* M       = (const float*)d_in[1];
    const unsigned char* mask = (const unsigned char*)d_in[2];
    const int*   lengths = (const int*)d_in[3];
    const float* emb     = (const float*)d_in[4];
    const float* Wq      = (const float*)d_in[5];
    const float* bq      = (const float*)d_in[6];
    const float* Wc      = (const float*)d_in[7];
    const float* bc      = (const float*)d_in[8];
    const float* W_ih    = (const float*)d_in[9];
    const float* W_hh    = (const float*)d_in[10];
    const float* b_ih    = (const float*)d_in[11];
    const float* b_hh    = (const float*)d_in[12];
    float* out = (float*)d_out;

    float* ws      = (float*)d_ws;
    float* h       = ws;                    // 1024*512
    float* c       = ws + 524288;           // 1024*512
    float* pq      = ws + 1048576;          // 1024*256
    float* applied = ws + 1310720;          // 1024*256
    float* att     = ws + 1572864;          // 1024*512
    int*   flag    = (int*)(ws + 2097152);  // 1 int

    hipMemsetAsync(h, 0, 524288 * 4, stream);
    hipMemsetAsync(c, 0, 524288 * 4, stream);
    hipMemsetAsync(flag, 0, 4, stream);
    hipMemsetAsync(out + (size_t)NB * L_, 0, 2 * NB * 4, stream);  // logits+entropy = 0

    detect_mask<<<128, 256, 0, stream>>>(mask, flag);

    for (int t = 0; t < T_; ++t) {
        // pq = h @ Wq.T + bq     (1024x256, K=512)
        gemm64<<<dim3(4, 16), 256, 0, stream>>>(h, h, Wq, bq, pq, 256, 512, 512);
        // attention (+ write selected w into out)
        attend_kernel<<<NB, 256, 0, stream>>>(M, mask, flag, pq, lengths, applied, out, t, 1);
        // att_out = [applied|h] @ Wc.T + bc   (1024x512, K=768)
        gemm64<<<dim3(8, 16), 256, 0, stream>>>(applied, h, Wc, bc, att, 512, 768, 256);
        // gates + LSTM cell, updates h,c in place
        gates_lstm<<<dim3(8, 16), 256, 0, stream>>>(emb, msg, att, W_ih, W_hh, b_ih, b_hh, h, c, t);
    }
    // final attention at t=T (w_last), no applied needed
    gemm64<<<dim3(4, 16), 256, 0, stream>>>(h, h, Wq, bq, pq, 256, 512, 512);
    attend_kernel<<<NB, 256, 0, stream>>>(M, mask, flag, pq, lengths, applied, out, T_, 0);
}

// Round 2
// 2505.476 us; speedup vs baseline: 2.7175x; 2.7175x over previous
//
#include <hip/hip_runtime.h>
#include <math.h>

// Problem dims (fixed per reference)
#define NB 1024   // batch
#define L_ 128    // objects
#define E_ 256    // embed dim
#define H_ 512    // hidden
#define T_ 20     // timesteps

typedef _Float16 h8 __attribute__((ext_vector_type(8)));
typedef float f4 __attribute__((ext_vector_type(4)));

// ---------------------------------------------------------------------------
// Mask-dtype detector (unchanged from round 1, verified working)
// ---------------------------------------------------------------------------
__global__ __launch_bounds__(256) void detect_mask(const unsigned char* __restrict__ mask,
                                                   int* __restrict__ flag) {
    int i = blockIdx.x * 256 + threadIdx.x;          // i < 32768
    if (mask[4 * i + 1] != 0) flag[0] = 1;           // benign race, same value
}

// ---------------------------------------------------------------------------
// attend (unchanged from round 1, verified working)
// ---------------------------------------------------------------------------
__global__ __launch_bounds__(256) void attend_kernel(
    const float* __restrict__ M, const unsigned char* __restrict__ maskB,
    const int* __restrict__ flag, const float* __restrict__ pq,
    const int* __restrict__ lengths, float* __restrict__ applied,
    float* __restrict__ out, int t, int writeApplied)
{
    const int b = blockIdx.x;
    const int tid = threadIdx.x;
    __shared__ float pq_s[E_];
    __shared__ float sc[L_];
    __shared__ float red[8];

    pq_s[tid] = pq[b * E_ + tid];
    __syncthreads();

    const int wave = tid >> 6, lane = tid & 63;
    const float* Mb = M + (size_t)b * L_ * E_;
    const int isByte = flag[0];
    const int* maskI = (const int*)maskB;

    for (int l = wave; l < L_; l += 4) {
        float4 mv = *reinterpret_cast<const float4*>(Mb + l * E_ + lane * 4);
        float4 pv = *reinterpret_cast<const float4*>(pq_s + lane * 4);
        float s = mv.x * pv.x + mv.y * pv.y + mv.z * pv.z + mv.w * pv.w;
        #pragma unroll
        for (int off = 32; off > 0; off >>= 1) s += __shfl_down(s, off, 64);
        if (lane == 0) {
            int msk = isByte ? (int)maskB[b * L_ + l] : maskI[b * L_ + l];
            sc[l] = msk ? -INFINITY : s;
        }
    }
    __syncthreads();

    float v = (tid < L_) ? sc[tid] : -INFINITY;
    float m = v;
    #pragma unroll
    for (int off = 32; off > 0; off >>= 1) m = fmaxf(m, __shfl_down(m, off, 64));
    if (lane == 0) red[wave] = m;
    __syncthreads();
    const float mx = fmaxf(fmaxf(red[0], red[1]), fmaxf(red[2], red[3]));
    const float e = (tid < L_) ? __expf(v - mx) : 0.0f;
    float s2 = e;
    #pragma unroll
    for (int off = 32; off > 0; off >>= 1) s2 += __shfl_down(s2, off, 64);
    if (lane == 0) red[4 + wave] = s2;
    __syncthreads();
    const float tot = red[4] + red[5] + red[6] + red[7];
    const float wgt = e / tot;
    if (tid < L_) sc[tid] = wgt;
    __syncthreads();

    int lc = lengths[b];
    lc = lc < 0 ? 0 : (lc > T_ ? T_ : lc);
    if (lc == t && tid < L_) out[(size_t)b * L_ + tid] = wgt;

    if (writeApplied) {
        float acc = 0.0f;
        #pragma unroll 8
        for (int l = 0; l < L_; ++l) acc += sc[l] * Mb[l * E_ + tid];
        applied[b * E_ + tid] = acc;
    }
}

// ---------------------------------------------------------------------------
// f32 -> (f16 hi, f16 lo*2048) split
// ---------------------------------------------------------------------------
__device__ inline void cvt8(const float4& x0, const float4& x1, h8& hi, h8& lo) {
    float xs[8] = {x0.x, x0.y, x0.z, x0.w, x1.x, x1.y, x1.z, x1.w};
    #pragma unroll
    for (int e = 0; e < 8; ++e) {
        _Float16 hh = (_Float16)xs[e];
        hi[e] = hh;
        lo[e] = (_Float16)((xs[e] - (float)hh) * 2048.0f);
    }
}

// ---------------------------------------------------------------------------
// Split-f16 MFMA GEMM: C[m,n] = sum_k A[m,k]*B[n,k] + bias[n]
// A virtual concat: cols [0,K1) from A1 (stride K1, optional row gather via
// gidx[row*T_+t]), cols [K1,Kn) from A2 (stride Kn-K1).
// B virtual concat: cols [0,BK1) from B1 (stride BK1), rest from B2.
// 64x64 tile, 4 waves (2x2), wave = 32x32 via 2x2 16x16x32 fragments.
// Numerics: x = hi + lo*2^-11 (both f16); C = hihi + 2^-11*(hilo + lohi).
// Layout safety: A and B frags use IDENTICAL (lane&15 -> row, (lane>>4,elem)
// -> k) fills, so any HW k-slot permutation cancels in the dot product.
// ---------------------------------------------------------------------------
__global__ __launch_bounds__(256) void gemm_hilo(
    const float* __restrict__ A1, const float* __restrict__ A2, int K1,
    const int* __restrict__ gidx, int t,
    const float* __restrict__ B1, const float* __restrict__ B2, int BK1,
    const float* __restrict__ bias, float* __restrict__ C, int Nn, int Kn)
{
    __shared__ __align__(16) _Float16 Ah[64][40];
    __shared__ __align__(16) _Float16 Al[64][40];
    __shared__ __align__(16) _Float16 Bh[64][40];
    __shared__ __align__(16) _Float16 Bl[64][40];

    const int tid = threadIdx.x;
    const int n0 = blockIdx.x * 64, m0 = blockIdx.y * 64;
    const int lane = tid & 63, wv = tid >> 6;
    const int wr = (wv >> 1) * 32, wc = (wv & 1) * 32;   // wave tile origin
    const int fr = lane & 15, kg = (lane >> 4) * 8;      // frag row/col, k-slot
    const int sr = tid >> 2, skq = (tid & 3) * 8;        // staging row, k-chunk

    f4 acc1[2][2] = {};
    f4 acc2[2][2] = {};
    const int KnmK1 = Kn - K1;
    const int KnmB  = Kn - BK1;

    for (int k0 = 0; k0 < Kn; k0 += 32) {
        // stage A tile (64 x 32 f32 -> hi/lo f16)
        {
            const int k = k0 + skq;
            const float* src;
            if (k < K1) {
                const int rr = gidx ? gidx[(m0 + sr) * T_ + t] : (m0 + sr);
                src = A1 + (size_t)rr * K1 + k;
            } else {
                src = A2 + (size_t)(m0 + sr) * KnmK1 + (k - K1);
            }
            float4 x0 = *reinterpret_cast<const float4*>(src);
            float4 x1 = *reinterpret_cast<const float4*>(src + 4);
            h8 hi, lo;
            cvt8(x0, x1, hi, lo);
            *reinterpret_cast<h8*>(&Ah[sr][skq]) = hi;
            *reinterpret_cast<h8*>(&Al[sr][skq]) = lo;
        }
        // stage B tile
        {
            const int k = k0 + skq;
            const float* src;
            if (k < BK1) src = B1 + (size_t)(n0 + sr) * BK1 + k;
            else         src = B2 + (size_t)(n0 + sr) * KnmB + (k - BK1);
            float4 x0 = *reinterpret_cast<const float4*>(src);
            float4 x1 = *reinterpret_cast<const float4*>(src + 4);
            h8 hi, lo;
            cvt8(x0, x1, hi, lo);
            *reinterpret_cast<h8*>(&Bh[sr][skq]) = hi;
            *reinterpret_cast<h8*>(&Bl[sr][skq]) = lo;
        }
        __syncthreads();

        h8 ah[2], al[2], bh[2], bl[2];
        #pragma unroll
        for (int i = 0; i < 2; ++i) {
            ah[i] = *reinterpret_cast<const h8*>(&Ah[wr + i * 16 + fr][kg]);
            al[i] = *reinterpret_cast<const h8*>(&Al[wr + i * 16 + fr][kg]);
            bh[i] = *reinterpret_cast<const h8*>(&Bh[wc + i * 16 + fr][kg]);
            bl[i] = *reinterpret_cast<const h8*>(&Bl[wc + i * 16 + fr][kg]);
        }
        #pragma unroll
        for (int i = 0; i < 2; ++i)
            #pragma unroll
            for (int j = 0; j < 2; ++j) {
                acc1[i][j] = __builtin_amdgcn_mfma_f32_16x16x32_f16(ah[i], bh[j], acc1[i][j], 0, 0, 0);
                acc2[i][j] = __builtin_amdgcn_mfma_f32_16x16x32_f16(ah[i], bl[j], acc2[i][j], 0, 0, 0);
                acc2[i][j] = __builtin_amdgcn_mfma_f32_16x16x32_f16(al[i], bh[j], acc2[i][j], 0, 0, 0);
            }
        __syncthreads();
    }

    // epilogue: C/D layout (m89-verified): col = lane&15, row = 4*(lane>>4)+reg
    const int crow0 = m0 + wr + (lane >> 4) * 4;
    const int ccol0 = n0 + wc + fr;
    #pragma unroll
    for (int i = 0; i < 2; ++i)
        #pragma unroll
        for (int j = 0; j < 2; ++j) {
            const int col = ccol0 + j * 16;
            const float bv = bias[col];
            #pragma unroll
            for (int r = 0; r < 4; ++r) {
                const int row = crow0 + i * 16 + r;
                C[(size_t)row * Nn + col] =
                    acc1[i][j][r] + acc2[i][j][r] * (1.0f / 2048.0f) + bv;
            }
        }
}

// ---------------------------------------------------------------------------
// LSTM cell elementwise. gates (1024 x 2048) already contains x@W_ih.T +
// att@W_hh.T + b_ih (from GEMM bias); add b_hh here. float4 per thread.
// ---------------------------------------------------------------------------
__global__ __launch_bounds__(256) void lstm_cell(
    const float* __restrict__ gates, const float* __restrict__ b_hh,
    float* __restrict__ h, float* __restrict__ c)
{
    const int idx = blockIdx.x * 256 + threadIdx.x;   // 0 .. 131071
    const int b = idx >> 7, q = (idx & 127) * 4;
    const float* gb = gates + (size_t)b * 2048;
    const float4 gi = *reinterpret_cast<const float4*>(gb + q);
    const float4 gf = *reinterpret_cast<const float4*>(gb + 512 + q);
    const float4 gg = *reinterpret_cast<const float4*>(gb + 1024 + q);
    const float4 go = *reinterpret_cast<const float4*>(gb + 1536 + q);
    const float4 bi = *reinterpret_cast<const float4*>(b_hh + q);
    const float4 bf = *reinterpret_cast<const float4*>(b_hh + 512 + q);
    const float4 bg = *reinterpret_cast<const float4*>(b_hh + 1024 + q);
    const float4 bo = *reinterpret_cast<const float4*>(b_hh + 1536 + q);
    const size_t hidx = (size_t)b * H_ + q;
    float4 cv = *reinterpret_cast<const float4*>(c + hidx);
    float4 hn, cn;
    const float* pi = (const float*)&gi; const float* pf = (const float*)&gf;
    const float* pg = (const float*)&gg; const float* po = (const float*)&go;
    const float* qi = (const float*)&bi; const float* qf = (const float*)&bf;
    const float* qg = (const float*)&bg; const float* qo = (const float*)&bo;
    float* pc = (float*)&cv; float* oc = (float*)&cn; float* oh = (float*)&hn;
    #pragma unroll
    for (int e = 0; e < 4; ++e) {
        const float vi = pi[e] + qi[e], vf = pf[e] + qf[e];
        const float vg = pg[e] + qg[e], vo = po[e] + qo[e];
        const float si = 1.0f / (1.0f + __expf(-vi));
        const float sf = 1.0f / (1.0f + __expf(-vf));
        const float so = 1.0f / (1.0f + __expf(-vo));
        const float tg = tanhf(vg);
        const float cnew = sf * pc[e] + si * tg;
        oc[e] = cnew;
        oh[e] = so * tanhf(cnew);
    }
    *reinterpret_cast<float4*>(c + hidx) = cn;
    *reinterpret_cast<float4*>(h + hidx) = hn;
}

// ---------------------------------------------------------------------------
extern "C" void kernel_launch(void* const* d_in, const int* in_sizes, int n_in,
                              void* d_out, int out_size, void* d_ws, size_t ws_size,
                              hipStream_t stream)
{
    const int*   msg     = (const int*)d_in[0];
    const float* M       = (const float*)d_in[1];
    const unsigned char* mask = (const unsigned char*)d_in[2];
    const int*   lengths = (const int*)d_in[3];
    const float* emb     = (const float*)d_in[4];
    const float* Wq      = (const float*)d_in[5];
    const float* bq      = (const float*)d_in[6];
    const float* Wc      = (const float*)d_in[7];
    const float* bc      = (const float*)d_in[8];
    const float* W_ih    = (const float*)d_in[9];
    const float* W_hh    = (const float*)d_in[10];
    const float* b_ih    = (const float*)d_in[11];
    const float* b_hh    = (const float*)d_in[12];
    float* out = (float*)d_out;

    float* ws      = (float*)d_ws;
    float* h       = ws;                      // 1024*512
    float* c       = ws + 524288;             // 1024*512
    float* pq      = ws + 1048576;            // 1024*256
    float* applied = ws + 1310720;            // 1024*256
    float* att     = ws + 1572864;            // 1024*512
    float* gates   = ws + 2097152;            // 1024*2048
    int*   flag    = (int*)(ws + 4194304);    // 1 int

    hipMemsetAsync(h, 0, 524288 * 4, stream);
    hipMemsetAsync(c, 0, 524288 * 4, stream);
    hipMemsetAsync(flag, 0, 4, stream);
    hipMemsetAsync(out + (size_t)NB * L_, 0, 2 * NB * 4, stream);  // logits+entropy

    detect_mask<<<128, 256, 0, stream>>>(mask, flag);

    for (int t = 0; t < T_; ++t) {
        // pq = h @ Wq.T + bq        (1024 x 256, K=512)
        gemm_hilo<<<dim3(4, 16), 256, 0, stream>>>(
            h, h, 512, nullptr, 0, Wq, Wq, 512, bq, pq, 256, 512);
        // attention (+ write selected w into out)
        attend_kernel<<<NB, 256, 0, stream>>>(M, mask, flag, pq, lengths, applied, out, t, 1);
        // att_out = [applied|h] @ Wc.T + bc   (1024 x 512, K=768)
        gemm_hilo<<<dim3(8, 16), 256, 0, stream>>>(
            applied, h, 256, nullptr, 0, Wc, Wc, 768, bc, att, 512, 768);
        // gates = [emb[msg[:,t]] | att] @ [W_ih|W_hh].T + b_ih  (1024 x 2048, K=768)
        gemm_hilo<<<dim3(32, 16), 256, 0, stream>>>(
            emb, att, 256, msg, t, W_ih, W_hh, 256, b_ih, gates, 2048, 768);
        // LSTM cell (adds b_hh), updates h,c
        lstm_cell<<<512, 256, 0, stream>>>(gates, b_hh, h, c);
    }
    // final attention at t=T (w_last), no applied needed
    gemm_hilo<<<dim3(4, 16), 256, 0, stream>>>(
        h, h, 512, nullptr, 0, Wq, Wq, 512, bq, pq, 256, 512);
    attend_kernel<<<NB, 256, 0, stream>>>(M, mask, flag, pq, lengths, applied, out, T_, 0);
}

// Round 5
// 2436.463 us; speedup vs baseline: 2.7945x; 1.0283x over previous
//
#include <hip/hip_runtime.h>
#include <math.h>

// Problem dims (fixed per reference)
#define NB 1024   // batch
#define L_ 128    // objects
#define E_ 256    // embed dim
#define H_ 512    // hidden
#define T_ 20     // timesteps
#define CH 32     // attend: rows per chunk
#define NCH 4     // attend: chunks per batch (L_/CH)

typedef _Float16 h8 __attribute__((ext_vector_type(8)));
typedef float f4 __attribute__((ext_vector_type(4)));

// ---------------------------------------------------------------------------
// Mask-dtype detector (verified working)
// ---------------------------------------------------------------------------
__global__ __launch_bounds__(256) void detect_mask(const unsigned char* __restrict__ mask,
                                                   int* __restrict__ flag) {
    int i = blockIdx.x * 256 + threadIdx.x;          // i < 32768
    if (mask[4 * i + 1] != 0) flag[0] = 1;           // benign race, same value
}

// ---------------------------------------------------------------------------
// attend K1: per (chunk s, batch b) block. scores for 32 rows, chunk-local
// softmax stats (m_s, sum_s), unnormalized p, and partial applied_s.
// ---------------------------------------------------------------------------
__global__ __launch_bounds__(256) void attend_part(
    const float* __restrict__ M, const unsigned char* __restrict__ maskB,
    const int* __restrict__ flag, const float* __restrict__ pq,
    float* __restrict__ pbuf,      // [NB][L_] unnormalized exp
    float* __restrict__ apart,     // [NB][NCH][E_] partial applied
    float2* __restrict__ stats)    // [NB][NCH] = (m_s, sum_s)
{
    const int s = blockIdx.x, b = blockIdx.y;
    const int tid = threadIdx.x;
    __shared__ float pq_s[E_];
    __shared__ float ps[CH];

    pq_s[tid] = pq[b * E_ + tid];
    __syncthreads();

    const int wave = tid >> 6, lane = tid & 63;
    const int r = lane >> 3, i = lane & 7;          // 8 rows/wave, 8 lanes/row
    const int l = wave * 8 + r;                     // 0..31 within chunk
    const float* Mrow = M + ((size_t)b * L_ + s * CH + l) * E_;

    // scores: 8 lanes per row, each 8 x float4
    float acc = 0.f;
    #pragma unroll
    for (int j = 0; j < 8; ++j) {
        float4 mv = *reinterpret_cast<const float4*>(Mrow + i * 4 + j * 32);
        float4 pv = *reinterpret_cast<const float4*>(pq_s + i * 4 + j * 32);
        acc += mv.x * pv.x + mv.y * pv.y + mv.z * pv.z + mv.w * pv.w;
    }
    acc += __shfl_down(acc, 4, 64);
    acc += __shfl_down(acc, 2, 64);
    acc += __shfl_down(acc, 1, 64);

    __shared__ float sc[CH];
    if (i == 0) {
        const int lg = s * CH + l;
        int msk = flag[0] ? (int)maskB[b * L_ + lg] : ((const int*)maskB)[b * L_ + lg];
        sc[l] = msk ? -INFINITY : acc;
    }
    __syncthreads();

    // chunk max / exp / sum on wave 0
    if (wave == 0) {
        const float v = (lane < CH) ? sc[lane] : -INFINITY;
        float m = v;
        #pragma unroll
        for (int off = 32; off > 0; off >>= 1) m = fmaxf(m, __shfl_down(m, off, 64));
        m = __shfl(m, 0, 64);
        // all-masked chunk -> m = -inf -> p = 0 (guard NaN from (-inf)-(-inf))
        const float p = (lane < CH && !isinf(m)) ? __expf(v - m) : 0.f;
        float ss = p;
        #pragma unroll
        for (int off = 32; off > 0; off >>= 1) ss += __shfl_down(ss, off, 64);
        if (lane == 0) stats[b * NCH + s] = make_float2(m, ss);
        if (lane < CH) {
            ps[lane] = p;
            pbuf[b * L_ + s * CH + lane] = p;
        }
    }
    __syncthreads();

    // partial applied: thread = e, 32-row weighted sum (rows hit L2)
    const float* Mc = M + ((size_t)b * L_ + s * CH) * E_;
    float a = 0.f;
    #pragma unroll 8
    for (int l2 = 0; l2 < CH; ++l2) a += ps[l2] * Mc[l2 * E_ + tid];
    apart[((size_t)b * NCH + s) * E_ + tid] = a;
}

// ---------------------------------------------------------------------------
// attend K2: combine chunk partials -> applied; write w row at t==clip(len).
// ---------------------------------------------------------------------------
__global__ __launch_bounds__(256) void attend_combine(
    const float* __restrict__ pbuf, const float* __restrict__ apart,
    const float2* __restrict__ stats, const int* __restrict__ lengths,
    float* __restrict__ applied, float* __restrict__ out, int t, int writeApplied)
{
    const int b = blockIdx.x;
    const int tid = threadIdx.x;
    __shared__ float scale[NCH];
    __shared__ float zinv;

    if (tid == 0) {
        float m = -INFINITY;
        #pragma unroll
        for (int s = 0; s < NCH; ++s) m = fmaxf(m, stats[b * NCH + s].x);
        float Z = 0.f;
        #pragma unroll
        for (int s = 0; s < NCH; ++s) {
            const float2 st = stats[b * NCH + s];
            const float sc = isinf(st.x) ? 0.f : __expf(st.x - m);
            scale[s] = sc;
            Z += st.y * sc;
        }
        zinv = 1.f / Z;     // >= 1 unmasked slot guaranteed -> Z >= 1
    }
    __syncthreads();

    if (writeApplied) {
        float a = 0.f;
        #pragma unroll
        for (int s = 0; s < NCH; ++s)
            a += apart[((size_t)b * NCH + s) * E_ + tid] * scale[s];
        applied[b * E_ + tid] = a * zinv;
    }

    int lc = lengths[b];
    lc = lc < 0 ? 0 : (lc > T_ ? T_ : lc);
    if (lc == t && tid < L_)
        out[(size_t)b * L_ + tid] = pbuf[b * L_ + tid] * scale[tid >> 5] * zinv;
}

// ---------------------------------------------------------------------------
// f32 -> (f16 hi, f16 lo*2048) split
// ---------------------------------------------------------------------------
__device__ inline void cvt8(const float4& x0, const float4& x1, h8& hi, h8& lo) {
    float xs[8] = {x0.x, x0.y, x0.z, x0.w, x1.x, x1.y, x1.z, x1.w};
    #pragma unroll
    for (int e = 0; e < 8; ++e) {
        _Float16 hh = (_Float16)xs[e];
        hi[e] = hh;
        lo[e] = (_Float16)((xs[e] - (float)hh) * 2048.0f);
    }
}

// ---------------------------------------------------------------------------
// Split-f16 MFMA GEMM (verified in round 2): C[m,n] = sum_k A[m,k]*B[n,k]+bias
// ---------------------------------------------------------------------------
__global__ __launch_bounds__(256) void gemm_hilo(
    const float* __restrict__ A1, const float* __restrict__ A2, int K1,
    const int* __restrict__ gidx, int t,
    const float* __restrict__ B1, const float* __restrict__ B2, int BK1,
    const float* __restrict__ bias, float* __restrict__ C, int Nn, int Kn)
{
    __shared__ __align__(16) _Float16 Ah[64][40];
    __shared__ __align__(16) _Float16 Al[64][40];
    __shared__ __align__(16) _Float16 Bh[64][40];
    __shared__ __align__(16) _Float16 Bl[64][40];

    const int tid = threadIdx.x;
    const int n0 = blockIdx.x * 64, m0 = blockIdx.y * 64;
    const int lane = tid & 63, wv = tid >> 6;
    const int wr = (wv >> 1) * 32, wc = (wv & 1) * 32;
    const int fr = lane & 15, kg = (lane >> 4) * 8;
    const int sr = tid >> 2, skq = (tid & 3) * 8;

    f4 acc1[2][2] = {};
    f4 acc2[2][2] = {};
    const int KnmK1 = Kn - K1;
    const int KnmB  = Kn - BK1;

    for (int k0 = 0; k0 < Kn; k0 += 32) {
        {
            const int k = k0 + skq;
            const float* src;
            if (k < K1) {
                const int rr = gidx ? gidx[(m0 + sr) * T_ + t] : (m0 + sr);
                src = A1 + (size_t)rr * K1 + k;
            } else {
                src = A2 + (size_t)(m0 + sr) * KnmK1 + (k - K1);
            }
            float4 x0 = *reinterpret_cast<const float4*>(src);
            float4 x1 = *reinterpret_cast<const float4*>(src + 4);
            h8 hi, lo;
            cvt8(x0, x1, hi, lo);
            *reinterpret_cast<h8*>(&Ah[sr][skq]) = hi;
            *reinterpret_cast<h8*>(&Al[sr][skq]) = lo;
        }
        {
            const int k = k0 + skq;
            const float* src;
            if (k < BK1) src = B1 + (size_t)(n0 + sr) * BK1 + k;
            else         src = B2 + (size_t)(n0 + sr) * KnmB + (k - BK1);
            float4 x0 = *reinterpret_cast<const float4*>(src);
            float4 x1 = *reinterpret_cast<const float4*>(src + 4);
            h8 hi, lo;
            cvt8(x0, x1, hi, lo);
            *reinterpret_cast<h8*>(&Bh[sr][skq]) = hi;
            *reinterpret_cast<h8*>(&Bl[sr][skq]) = lo;
        }
        __syncthreads();

        h8 ah[2], al[2], bh[2], bl[2];
        #pragma unroll
        for (int i = 0; i < 2; ++i) {
            ah[i] = *reinterpret_cast<const h8*>(&Ah[wr + i * 16 + fr][kg]);
            al[i] = *reinterpret_cast<const h8*>(&Al[wr + i * 16 + fr][kg]);
            bh[i] = *reinterpret_cast<const h8*>(&Bh[wc + i * 16 + fr][kg]);
            bl[i] = *reinterpret_cast<const h8*>(&Bl[wc + i * 16 + fr][kg]);
        }
        #pragma unroll
        for (int i = 0; i < 2; ++i)
            #pragma unroll
            for (int j = 0; j < 2; ++j) {
                acc1[i][j] = __builtin_amdgcn_mfma_f32_16x16x32_f16(ah[i], bh[j], acc1[i][j], 0, 0, 0);
                acc2[i][j] = __builtin_amdgcn_mfma_f32_16x16x32_f16(ah[i], bl[j], acc2[i][j], 0, 0, 0);
                acc2[i][j] = __builtin_amdgcn_mfma_f32_16x16x32_f16(al[i], bh[j], acc2[i][j], 0, 0, 0);
            }
        __syncthreads();
    }

    const int crow0 = m0 + wr + (lane >> 4) * 4;
    const int ccol0 = n0 + wc + fr;
    #pragma unroll
    for (int i = 0; i < 2; ++i)
        #pragma unroll
        for (int j = 0; j < 2; ++j) {
            const int col = ccol0 + j * 16;
            const float bv = bias[col];
            #pragma unroll
            for (int r = 0; r < 4; ++r) {
                const int row = crow0 + i * 16 + r;
                C[(size_t)row * Nn + col] =
                    acc1[i][j][r] + acc2[i][j][r] * (1.0f / 2048.0f) + bv;
            }
        }
}

// ---------------------------------------------------------------------------
// LSTM cell elementwise (verified in round 2)
// ---------------------------------------------------------------------------
__global__ __launch_bounds__(256) void lstm_cell(
    const float* __restrict__ gates, const float* __restrict__ b_hh,
    float* __restrict__ h, float* __restrict__ c)
{
    const int idx = blockIdx.x * 256 + threadIdx.x;   // 0 .. 131071
    const int b = idx >> 7, q = (idx & 127) * 4;
    const float* gb = gates + (size_t)b * 2048;
    const float4 gi = *reinterpret_cast<const float4*>(gb + q);
    const float4 gf = *reinterpret_cast<const float4*>(gb + 512 + q);
    const float4 gg = *reinterpret_cast<const float4*>(gb + 1024 + q);
    const float4 go = *reinterpret_cast<const float4*>(gb + 1536 + q);
    const float4 bi = *reinterpret_cast<const float4*>(b_hh + q);
    const float4 bf = *reinterpret_cast<const float4*>(b_hh + 512 + q);
    const float4 bg = *reinterpret_cast<const float4*>(b_hh + 1024 + q);
    const float4 bo = *reinterpret_cast<const float4*>(b_hh + 1536 + q);
    const size_t hidx = (size_t)b * H_ + q;
    float4 cv = *reinterpret_cast<const float4*>(c + hidx);
    float4 hn, cn;
    const float* pi = (const float*)&gi; const float* pf = (const float*)&gf;
    const float* pg = (const float*)&gg; const float* po = (const float*)&go;
    const float* qi = (const float*)&bi; const float* qf = (const float*)&bf;
    const float* qg = (const float*)&bg; const float* qo = (const float*)&bo;
    float* pc = (float*)&cv; float* oc = (float*)&cn; float* oh = (float*)&hn;
    #pragma unroll
    for (int e = 0; e < 4; ++e) {
        const float vi = pi[e] + qi[e], vf = pf[e] + qf[e];
        const float vg = pg[e] + qg[e], vo = po[e] + qo[e];
        const float si = 1.0f / (1.0f + __expf(-vi));
        const float sf = 1.0f / (1.0f + __expf(-vf));
        const float so = 1.0f / (1.0f + __expf(-vo));
        const float tg = tanhf(vg);
        const float cnew = sf * pc[e] + si * tg;
        oc[e] = cnew;
        oh[e] = so * tanhf(cnew);
    }
    *reinterpret_cast<float4*>(c + hidx) = cn;
    *reinterpret_cast<float4*>(h + hidx) = hn;
}

// ---------------------------------------------------------------------------
extern "C" void kernel_launch(void* const* d_in, const int* in_sizes, int n_in,
                              void* d_out, int out_size, void* d_ws, size_t ws_size,
                              hipStream_t stream)
{
    const int*   msg     = (const int*)d_in[0];
    const float* M       = (const float*)d_in[1];
    const unsigned char* mask = (const unsigned char*)d_in[2];
    const int*   lengths = (const int*)d_in[3];
    const float* emb     = (const float*)d_in[4];
    const float* Wq      = (const float*)d_in[5];
    const float* bq      = (const float*)d_in[6];
    const float* Wc      = (const float*)d_in[7];
    const float* bc      = (const float*)d_in[8];
    const float* W_ih    = (const float*)d_in[9];
    const float* W_hh    = (const float*)d_in[10];
    const float* b_ih    = (const float*)d_in[11];
    const float* b_hh    = (const float*)d_in[12];
    float* out = (float*)d_out;

    // workspace layout (floats):
    //   h       [0,        524288)
    //   c       [524288,  1048576)
    //   pq      [1048576, 1310720)
    //   applied [1310720, 1572864)
    //   att     [1572864, 2097152)
    //   gates   [2097152, 4194304)
    //   flag    [4194304, 4194305)
    //   pbuf    [4194560, 4325632)
    //   apart   [4325632, 5374208)   = 4325632 + 1024*4*256
    //   stats   [5374208, 5382400)   (fixed: was 5373952, overlapped apart!)
    float*  ws      = (float*)d_ws;
    float*  h       = ws;
    float*  c       = ws + 524288;
    float*  pq      = ws + 1048576;
    float*  applied = ws + 1310720;
    float*  att     = ws + 1572864;
    float*  gates   = ws + 2097152;
    int*    flag    = (int*)(ws + 4194304);
    float*  pbuf    = ws + 4194560;
    float*  apart   = ws + 4325632;
    float2* stats   = (float2*)(ws + 5374208);

    hipMemsetAsync(h, 0, 524288 * 4, stream);
    hipMemsetAsync(c, 0, 524288 * 4, stream);
    hipMemsetAsync(flag, 0, 4, stream);
    hipMemsetAsync(out + (size_t)NB * L_, 0, 2 * NB * 4, stream);  // logits+entropy

    detect_mask<<<128, 256, 0, stream>>>(mask, flag);

    for (int t = 0; t < T_; ++t) {
        // pq = h @ Wq.T + bq        (1024 x 256, K=512)
        gemm_hilo<<<dim3(4, 16), 256, 0, stream>>>(
            h, h, 512, nullptr, 0, Wq, Wq, 512, bq, pq, 256, 512);
        // attention: partial (flash-style) + combine
        attend_part<<<dim3(NCH, NB), 256, 0, stream>>>(
            M, mask, flag, pq, pbuf, apart, stats);
        attend_combine<<<NB, 256, 0, stream>>>(
            pbuf, apart, stats, lengths, applied, out, t, 1);
        // att_out = [applied|h] @ Wc.T + bc   (1024 x 512, K=768)
        gemm_hilo<<<dim3(8, 16), 256, 0, stream>>>(
            applied, h, 256, nullptr, 0, Wc, Wc, 768, bc, att, 512, 768);
        // gates = [emb[msg[:,t]] | att] @ [W_ih|W_hh].T + b_ih  (1024 x 2048, K=768)
        gemm_hilo<<<dim3(32, 16), 256, 0, stream>>>(
            emb, att, 256, msg, t, W_ih, W_hh, 256, b_ih, gates, 2048, 768);
        // LSTM cell (adds b_hh), updates h,c
        lstm_cell<<<512, 256, 0, stream>>>(gates, b_hh, h, c);
    }
    // final attention at t=T (w_last)
    gemm_hilo<<<dim3(4, 16), 256, 0, stream>>>(
        h, h, 512, nullptr, 0, Wq, Wq, 512, bq, pq, 256, 512);
    attend_part<<<dim3(NCH, NB), 256, 0, stream>>>(
        M, mask, flag, pq, pbuf, apart, stats);
    attend_combine<<<NB, 256, 0, stream>>>(
        pbuf, apart, stats, lengths, applied, out, T_, 0);
}

// Round 6
// 2295.208 us; speedup vs baseline: 2.9665x; 1.0615x over previous
//
#include <hip/hip_runtime.h>
#include <math.h>

// Problem dims (fixed per reference)
#define NB 1024   // batch
#define L_ 128    // objects
#define E_ 256    // embed dim
#define H_ 512    // hidden
#define T_ 20     // timesteps
#define CH 32     // attend: rows per chunk
#define NCH 4     // attend: chunks per batch (L_/CH)

typedef _Float16 h8 __attribute__((ext_vector_type(8)));
typedef _Float16 h4 __attribute__((ext_vector_type(4)));
typedef float f4 __attribute__((ext_vector_type(4)));

// ---------------------------------------------------------------------------
// Mask-dtype detector (verified working)
// ---------------------------------------------------------------------------
__global__ __launch_bounds__(256) void detect_mask(const unsigned char* __restrict__ mask,
                                                   int* __restrict__ flag) {
    int i = blockIdx.x * 256 + threadIdx.x;          // i < 32768
    if (mask[4 * i + 1] != 0) flag[0] = 1;           // benign race, same value
}

// ---------------------------------------------------------------------------
// Weight prep: f32 -> (hi f16, lo f16 * 2048), run once per launch.
// ---------------------------------------------------------------------------
__global__ __launch_bounds__(256) void split_plain(const float* __restrict__ src,
                                                   _Float16* __restrict__ dh,
                                                   _Float16* __restrict__ dl, int n) {
    int i = blockIdx.x * 256 + threadIdx.x;
    if (i < n) {
        float x = src[i];
        _Float16 hh = (_Float16)x;
        dh[i] = hh;
        dl[i] = (_Float16)((x - (float)hh) * 2048.0f);
    }
}

// [W_ih | W_hh] -> Wg[2048][768] hi/lo
__global__ __launch_bounds__(256) void split_concat(const float* __restrict__ Wih,
                                                    const float* __restrict__ Whh,
                                                    _Float16* __restrict__ dh,
                                                    _Float16* __restrict__ dl) {
    int i = blockIdx.x * 256 + threadIdx.x;          // over 2048*768
    int r = i / 768, k = i - r * 768;
    float x = (k < 256) ? Wih[r * 256 + k] : Whh[r * 512 + (k - 256)];
    _Float16 hh = (_Float16)x;
    dh[i] = hh;
    dl[i] = (_Float16)((x - (float)hh) * 2048.0f);
}

// ---------------------------------------------------------------------------
// attend K1 (verified round 5): per (chunk s, batch b) block.
// ---------------------------------------------------------------------------
__global__ __launch_bounds__(256) void attend_part(
    const float* __restrict__ M, const unsigned char* __restrict__ maskB,
    const int* __restrict__ flag, const float* __restrict__ pq,
    float* __restrict__ pbuf,      // [NB][L_] unnormalized exp
    float* __restrict__ apart,     // [NB][NCH][E_] partial applied
    float2* __restrict__ stats)    // [NB][NCH] = (m_s, sum_s)
{
    const int s = blockIdx.x, b = blockIdx.y;
    const int tid = threadIdx.x;
    __shared__ float pq_s[E_];
    __shared__ float ps[CH];

    pq_s[tid] = pq[b * E_ + tid];
    __syncthreads();

    const int wave = tid >> 6, lane = tid & 63;
    const int r = lane >> 3, i = lane & 7;          // 8 rows/wave, 8 lanes/row
    const int l = wave * 8 + r;                     // 0..31 within chunk
    const float* Mrow = M + ((size_t)b * L_ + s * CH + l) * E_;

    float acc = 0.f;
    #pragma unroll
    for (int j = 0; j < 8; ++j) {
        float4 mv = *reinterpret_cast<const float4*>(Mrow + i * 4 + j * 32);
        float4 pv = *reinterpret_cast<const float4*>(pq_s + i * 4 + j * 32);
        acc += mv.x * pv.x + mv.y * pv.y + mv.z * pv.z + mv.w * pv.w;
    }
    acc += __shfl_down(acc, 4, 64);
    acc += __shfl_down(acc, 2, 64);
    acc += __shfl_down(acc, 1, 64);

    __shared__ float sc[CH];
    if (i == 0) {
        const int lg = s * CH + l;
        int msk = flag[0] ? (int)maskB[b * L_ + lg] : ((const int*)maskB)[b * L_ + lg];
        sc[l] = msk ? -INFINITY : acc;
    }
    __syncthreads();

    if (wave == 0) {
        const float v = (lane < CH) ? sc[lane] : -INFINITY;
        float m = v;
        #pragma unroll
        for (int off = 32; off > 0; off >>= 1) m = fmaxf(m, __shfl_down(m, off, 64));
        m = __shfl(m, 0, 64);
        const float p = (lane < CH && !isinf(m)) ? __expf(v - m) : 0.f;
        float ss = p;
        #pragma unroll
        for (int off = 32; off > 0; off >>= 1) ss += __shfl_down(ss, off, 64);
        if (lane == 0) stats[b * NCH + s] = make_float2(m, ss);
        if (lane < CH) {
            ps[lane] = p;
            pbuf[b * L_ + s * CH + lane] = p;
        }
    }
    __syncthreads();

    const float* Mc = M + ((size_t)b * L_ + s * CH) * E_;
    float a = 0.f;
    #pragma unroll 8
    for (int l2 = 0; l2 < CH; ++l2) a += ps[l2] * Mc[l2 * E_ + tid];
    apart[((size_t)b * NCH + s) * E_ + tid] = a;
}

// ---------------------------------------------------------------------------
// attend K2: combine partials -> applied (hi/lo f16); write w at t==clip(len).
// ---------------------------------------------------------------------------
__global__ __launch_bounds__(256) void attend_combine(
    const float* __restrict__ pbuf, const float* __restrict__ apart,
    const float2* __restrict__ stats, const int* __restrict__ lengths,
    _Float16* __restrict__ ap_h, _Float16* __restrict__ ap_l,
    float* __restrict__ out, int t, int writeApplied)
{
    const int b = blockIdx.x;
    const int tid = threadIdx.x;
    __shared__ float scale[NCH];
    __shared__ float zinv;

    if (tid == 0) {
        float m = -INFINITY;
        #pragma unroll
        for (int s = 0; s < NCH; ++s) m = fmaxf(m, stats[b * NCH + s].x);
        float Z = 0.f;
        #pragma unroll
        for (int s = 0; s < NCH; ++s) {
            const float2 st = stats[b * NCH + s];
            const float sc = isinf(st.x) ? 0.f : __expf(st.x - m);
            scale[s] = sc;
            Z += st.y * sc;
        }
        zinv = 1.f / Z;     // >= 1 unmasked slot guaranteed -> Z >= 1
    }
    __syncthreads();

    if (writeApplied) {
        float a = 0.f;
        #pragma unroll
        for (int s = 0; s < NCH; ++s)
            a += apart[((size_t)b * NCH + s) * E_ + tid] * scale[s];
        a *= zinv;
        _Float16 hh = (_Float16)a;
        ap_h[b * E_ + tid] = hh;
        ap_l[b * E_ + tid] = (_Float16)((a - (float)hh) * 2048.0f);
    }

    int lc = lengths[b];
    lc = lc < 0 ? 0 : (lc > T_ ? T_ : lc);
    if (lc == t && tid < L_)
        out[(size_t)b * L_ + tid] = pbuf[b * L_ + tid] * scale[tid >> 5] * zinv;
}

// ---------------------------------------------------------------------------
// Pre-split f16 MFMA GEMM: C[m,n] = sum_k A[m,k]*B[n,k] + bias[n]
// A virtual concat (hi/lo pairs): cols [0,K1) from A1 (stride K1, optional
// gather), cols [K1,Kn) from A2 (stride Kn-K1). B single pre-split (stride Kn).
// Outputs: Cf (f32) and/or Ch/Cl (hi/lo f16). Numerics identical to round 5.
// ---------------------------------------------------------------------------
__global__ __launch_bounds__(256) void gemm_f16(
    const _Float16* __restrict__ A1h, const _Float16* __restrict__ A1l, int K1,
    const int* __restrict__ gidx, int t,
    const _Float16* __restrict__ A2h, const _Float16* __restrict__ A2l,
    const _Float16* __restrict__ Bh, const _Float16* __restrict__ Bl,
    const float* __restrict__ bias, float* __restrict__ Cf,
    _Float16* __restrict__ Ch, _Float16* __restrict__ Cl,
    int Nn, int Kn)
{
    __shared__ __align__(16) _Float16 Ah_s[64][40];
    __shared__ __align__(16) _Float16 Al_s[64][40];
    __shared__ __align__(16) _Float16 Bh_s[64][40];
    __shared__ __align__(16) _Float16 Bl_s[64][40];

    const int tid = threadIdx.x;
    const int n0 = blockIdx.x * 64, m0 = blockIdx.y * 64;
    const int lane = tid & 63, wv = tid >> 6;
    const int wr = (wv >> 1) * 32, wc = (wv & 1) * 32;
    const int fr = lane & 15, kg = (lane >> 4) * 8;
    const int sr = tid >> 2, skq = (tid & 3) * 8;

    f4 acc1[2][2] = {};
    f4 acc2[2][2] = {};
    const int KnmK1 = Kn - K1;

    for (int k0 = 0; k0 < Kn; k0 += 32) {
        const int k = k0 + skq;
        const _Float16 *sh, *sl;
        if (k < K1) {
            const int rr = gidx ? gidx[(m0 + sr) * T_ + t] : (m0 + sr);
            sh = A1h + (size_t)rr * K1 + k;
            sl = A1l + (size_t)rr * K1 + k;
        } else {
            sh = A2h + (size_t)(m0 + sr) * KnmK1 + (k - K1);
            sl = A2l + (size_t)(m0 + sr) * KnmK1 + (k - K1);
        }
        *reinterpret_cast<h8*>(&Ah_s[sr][skq]) = *reinterpret_cast<const h8*>(sh);
        *reinterpret_cast<h8*>(&Al_s[sr][skq]) = *reinterpret_cast<const h8*>(sl);
        const _Float16* bp = Bh + (size_t)(n0 + sr) * Kn + k;
        const _Float16* blp = Bl + (size_t)(n0 + sr) * Kn + k;
        *reinterpret_cast<h8*>(&Bh_s[sr][skq]) = *reinterpret_cast<const h8*>(bp);
        *reinterpret_cast<h8*>(&Bl_s[sr][skq]) = *reinterpret_cast<const h8*>(blp);
        __syncthreads();

        h8 ah[2], al[2], bh[2], bl[2];
        #pragma unroll
        for (int i = 0; i < 2; ++i) {
            ah[i] = *reinterpret_cast<const h8*>(&Ah_s[wr + i * 16 + fr][kg]);
            al[i] = *reinterpret_cast<const h8*>(&Al_s[wr + i * 16 + fr][kg]);
            bh[i] = *reinterpret_cast<const h8*>(&Bh_s[wc + i * 16 + fr][kg]);
            bl[i] = *reinterpret_cast<const h8*>(&Bl_s[wc + i * 16 + fr][kg]);
        }
        #pragma unroll
        for (int i = 0; i < 2; ++i)
            #pragma unroll
            for (int j = 0; j < 2; ++j) {
                acc1[i][j] = __builtin_amdgcn_mfma_f32_16x16x32_f16(ah[i], bh[j], acc1[i][j], 0, 0, 0);
                acc2[i][j] = __builtin_amdgcn_mfma_f32_16x16x32_f16(ah[i], bl[j], acc2[i][j], 0, 0, 0);
                acc2[i][j] = __builtin_amdgcn_mfma_f32_16x16x32_f16(al[i], bh[j], acc2[i][j], 0, 0, 0);
            }
        __syncthreads();
    }

    // C/D layout (m89-verified): col = lane&15, row = 4*(lane>>4)+reg
    const int crow0 = m0 + wr + (lane >> 4) * 4;
    const int ccol0 = n0 + wc + fr;
    #pragma unroll
    for (int i = 0; i < 2; ++i)
        #pragma unroll
        for (int j = 0; j < 2; ++j) {
            const int col = ccol0 + j * 16;
            const float bv = bias[col];
            #pragma unroll
            for (int r = 0; r < 4; ++r) {
                const int row = crow0 + i * 16 + r;
                const float v = acc1[i][j][r] + acc2[i][j][r] * (1.0f / 2048.0f) + bv;
                const size_t idx = (size_t)row * Nn + col;
                if (Cf) Cf[idx] = v;
                if (Ch) {
                    _Float16 hh = (_Float16)v;
                    Ch[idx] = hh;
                    Cl[idx] = (_Float16)((v - (float)hh) * 2048.0f);
                }
            }
        }
}

// ---------------------------------------------------------------------------
// LSTM cell elementwise: h written as hi/lo f16 (h only feeds GEMM-A).
// ---------------------------------------------------------------------------
__global__ __launch_bounds__(256) void lstm_cell(
    const float* __restrict__ gates, const float* __restrict__ b_hh,
    _Float16* __restrict__ h_h, _Float16* __restrict__ h_l,
    float* __restrict__ c)
{
    const int idx = blockIdx.x * 256 + threadIdx.x;   // 0 .. 131071
    const int b = idx >> 7, q = (idx & 127) * 4;
    const float* gb = gates + (size_t)b * 2048;
    const float4 gi = *reinterpret_cast<const float4*>(gb + q);
    const float4 gf = *reinterpret_cast<const float4*>(gb + 512 + q);
    const float4 gg = *reinterpret_cast<const float4*>(gb + 1024 + q);
    const float4 go = *reinterpret_cast<const float4*>(gb + 1536 + q);
    const float4 bi = *reinterpret_cast<const float4*>(b_hh + q);
    const float4 bf = *reinterpret_cast<const float4*>(b_hh + 512 + q);
    const float4 bg = *reinterpret_cast<const float4*>(b_hh + 1024 + q);
    const float4 bo = *reinterpret_cast<const float4*>(b_hh + 1536 + q);
    const size_t hidx = (size_t)b * H_ + q;
    float4 cv = *reinterpret_cast<const float4*>(c + hidx);
    float4 cn;
    h4 hh_v, hl_v;
    const float* pi = (const float*)&gi; const float* pf = (const float*)&gf;
    const float* pg = (const float*)&gg; const float* po = (const float*)&go;
    const float* qi = (const float*)&bi; const float* qf = (const float*)&bf;
    const float* qg = (const float*)&bg; const float* qo = (const float*)&bo;
    float* pc = (float*)&cv; float* oc = (float*)&cn;
    #pragma unroll
    for (int e = 0; e < 4; ++e) {
        const float vi = pi[e] + qi[e], vf = pf[e] + qf[e];
        const float vg = pg[e] + qg[e], vo = po[e] + qo[e];
        const float si = 1.0f / (1.0f + __expf(-vi));
        const float sf = 1.0f / (1.0f + __expf(-vf));
        const float so = 1.0f / (1.0f + __expf(-vo));
        const float tg = tanhf(vg);
        const float cnew = sf * pc[e] + si * tg;
        oc[e] = cnew;
        const float hn = so * tanhf(cnew);
        _Float16 hh = (_Float16)hn;
        hh_v[e] = hh;
        hl_v[e] = (_Float16)((hn - (float)hh) * 2048.0f);
    }
    *reinterpret_cast<float4*>(c + hidx) = cn;
    *reinterpret_cast<h4*>(h_h + hidx) = hh_v;
    *reinterpret_cast<h4*>(h_l + hidx) = hl_v;
}

// ---------------------------------------------------------------------------
extern "C" void kernel_launch(void* const* d_in, const int* in_sizes, int n_in,
                              void* d_out, int out_size, void* d_ws, size_t ws_size,
                              hipStream_t stream)
{
    const int*   msg     = (const int*)d_in[0];
    const float* M       = (const float*)d_in[1];
    const unsigned char* mask = (const unsigned char*)d_in[2];
    const int*   lengths = (const int*)d_in[3];
    const float* emb     = (const float*)d_in[4];
    const float* Wq      = (const float*)d_in[5];
    const float* bq      = (const float*)d_in[6];
    const float* Wc      = (const float*)d_in[7];
    const float* bc      = (const float*)d_in[8];
    const float* W_ih    = (const float*)d_in[9];
    const float* W_hh    = (const float*)d_in[10];
    const float* b_ih    = (const float*)d_in[11];
    const float* b_hh    = (const float*)d_in[12];
    float* out = (float*)d_out;

    // f32 workspace layout (float offsets):
    //   c      [0,       524288)
    //   pq     [524288,  786432)
    //   gates  [786432,  2883584)
    //   pbuf   [2883584, 3014656)
    //   apart  [3014656, 4063232)
    //   stats  [4063232, 4071424)
    //   flag   [4071424, 4071425)
    //   f16 region starts at float offset 4071680 (16B aligned)
    float*  ws    = (float*)d_ws;
    float*  c     = ws;
    float*  pq    = ws + 524288;
    float*  gates = ws + 786432;
    float*  pbuf  = ws + 2883584;
    float*  apart = ws + 3014656;
    float2* stats = (float2*)(ws + 4063232);
    int*    flag  = (int*)(ws + 4071424);

    // f16 buffers (offsets in _Float16 units; all starts divisible by 8 -> 16B)
    _Float16* f16b = (_Float16*)(ws + 4071680);
    _Float16* h_h  = f16b;                    //  524288  (1024x512)
    _Float16* h_l  = f16b + 524288;
    _Float16* ap_h = f16b + 1048576;          //  262144  (1024x256)
    _Float16* ap_l = f16b + 1310720;
    _Float16* at_h = f16b + 1572864;          //  524288  (1024x512)
    _Float16* at_l = f16b + 2097152;
    _Float16* em_h = f16b + 2621440;          //  256256  (1001x256)
    _Float16* em_l = f16b + 2877696;
    _Float16* Wq_h = f16b + 3133952;          //  131072  (256x512)
    _Float16* Wq_l = f16b + 3265024;
    _Float16* Wc_h = f16b + 3396096;          //  393216  (512x768)
    _Float16* Wc_l = f16b + 3789312;
    _Float16* Wg_h = f16b + 4182528;          // 1572864  (2048x768)
    _Float16* Wg_l = f16b + 5755392;          // ends 7328256

    hipMemsetAsync(c, 0, 524288 * 4, stream);
    hipMemsetAsync(h_h, 0, 524288 * 2, stream);   // f16 zero == 0x0000
    hipMemsetAsync(h_l, 0, 524288 * 2, stream);
    hipMemsetAsync(flag, 0, 4, stream);
    hipMemsetAsync(out + (size_t)NB * L_, 0, 2 * NB * 4, stream);  // logits+entropy

    detect_mask<<<128, 256, 0, stream>>>(mask, flag);
    // one-time weight/emb pre-split (per launch; same work every call)
    split_plain<<<512, 256, 0, stream>>>(Wq, Wq_h, Wq_l, 131072);
    split_plain<<<1536, 256, 0, stream>>>(Wc, Wc_h, Wc_l, 393216);
    split_plain<<<1001, 256, 0, stream>>>(emb, em_h, em_l, 256256);
    split_concat<<<6144, 256, 0, stream>>>(W_ih, W_hh, Wg_h, Wg_l);

    for (int t = 0; t < T_; ++t) {
        // pq = h @ Wq.T + bq        (1024 x 256, K=512), f32 out
        gemm_f16<<<dim3(4, 16), 256, 0, stream>>>(
            h_h, h_l, 512, nullptr, 0, h_h, h_l, Wq_h, Wq_l,
            bq, pq, nullptr, nullptr, 256, 512);
        // attention: flash partial + combine (combine emits applied hi/lo)
        attend_part<<<dim3(NCH, NB), 256, 0, stream>>>(
            M, mask, flag, pq, pbuf, apart, stats);
        attend_combine<<<NB, 256, 0, stream>>>(
            pbuf, apart, stats, lengths, ap_h, ap_l, out, t, 1);
        // att = [applied|h] @ Wc.T + bc   (1024 x 512, K=768), f16 hi/lo out
        gemm_f16<<<dim3(8, 16), 256, 0, stream>>>(
            ap_h, ap_l, 256, nullptr, 0, h_h, h_l, Wc_h, Wc_l,
            bc, nullptr, at_h, at_l, 512, 768);
        // gates = [emb[msg[:,t]] | att] @ Wg.T + b_ih  (1024 x 2048, K=768)
        gemm_f16<<<dim3(32, 16), 256, 0, stream>>>(
            em_h, em_l, 256, msg, t, at_h, at_l, Wg_h, Wg_l,
            b_ih, gates, nullptr, nullptr, 2048, 768);
        // LSTM cell (adds b_hh), updates h (hi/lo) and c
        lstm_cell<<<512, 256, 0, stream>>>(gates, b_hh, h_h, h_l, c);
    }
    // final attention at t=T (w_last)
    gemm_f16<<<dim3(4, 16), 256, 0, stream>>>(
        h_h, h_l, 512, nullptr, 0, h_h, h_l, Wq_h, Wq_l,
        bq, pq, nullptr, nullptr, 256, 512);
    attend_part<<<dim3(NCH, NB), 256, 0, stream>>>(
        M, mask, flag, pq, pbuf, apart, stats);
    attend_combine<<<NB, 256, 0, stream>>>(
        pbuf, apart, stats, lengths, ap_h, ap_l, out, T_, 0);
}